// Round 1
// baseline (853.860 us; speedup 1.0000x reference)
//
#include <hip/hip_runtime.h>
#include <math.h>

// SpatialGNN: B=64, N=1024 (32x32 grid), D_FEAT=1024, CTX=512, S=32, T=4
#define NB 64
#define NNODES 1024
#define CTXD 512
#define SEQL 32

typedef __attribute__((ext_vector_type(8))) short short8;
typedef __attribute__((ext_vector_type(4))) float floatx4;

__device__ __forceinline__ float bf2f(unsigned short u) {
  union { unsigned int i; float f; } v; v.i = ((unsigned int)u) << 16; return v.f;
}
__device__ __forceinline__ unsigned short f2bf(float f) {
  union { float f; unsigned int i; } v; v.f = f;
  unsigned int r = v.i + 0x7fffu + ((v.i >> 16) & 1u);  // RNE
  return (unsigned short)(r >> 16);
}
__device__ __forceinline__ float elu1(float x) { return x > 0.f ? x : expm1f(x); }

__device__ __forceinline__ void gload16(const void* g, void* l) {
  __builtin_amdgcn_global_load_lds((const __attribute__((address_space(1))) void*)g,
                                   (__attribute__((address_space(3))) void*)l, 16, 0, 0);
}

// ---------------------------------------------------------------------------
// Pack weights to bf16: initKB_w [512][1024], W1 = W_w[:, :512] (row stride 1024)
// ---------------------------------------------------------------------------
__global__ __launch_bounds__(256) void pack_k(const float* __restrict__ kbw,
                                              const float* __restrict__ Ww,
                                              unsigned short* __restrict__ kb_bf,
                                              unsigned short* __restrict__ w1_bf) {
  int idx = blockIdx.x * 256 + threadIdx.x;
  if (idx < 512 * 1024) {
    kb_bf[idx] = f2bf(kbw[idx]);
  } else {
    int k2 = idx - 512 * 1024;            // 0..262143
    int c = k2 >> 9, kk = k2 & 511;
    w1_bf[k2] = f2bf(Ww[c * 1024 + kk]);
  }
}

// ---------------------------------------------------------------------------
// Command pipeline: per-batch-element, fully block-local. Produces
// bias2[t][b][c] = cmd[t][b] @ W2^T + W_b  (f32, exact)
// ---------------------------------------------------------------------------
__global__ __launch_bounds__(512) void cmd_pipeline(
    const float* __restrict__ q_enc, const float* __restrict__ lstm,
    const int* __restrict__ q_len,
    const float* __restrict__ qInput_w, const float* __restrict__ qInput_b,
    const float* __restrict__ qT_w, const float* __restrict__ qT_b,
    const float* __restrict__ cmd_w, const float* __restrict__ cmd_b,
    const float* __restrict__ W_w, const float* __restrict__ W_b,
    float* __restrict__ bias2) {
  int b = blockIdx.x;       // 64
  int c = threadIdx.x;      // 512
  __shared__ float q1s[512];
  __shared__ float us[512];
  __shared__ float red[512];
  __shared__ float atts[32];
  __shared__ float cmds[512];

  const float* qe = q_enc + b * 512;
  float a0 = qInput_b[c];
  for (int k = 0; k < 512; k++) a0 += qe[k] * qInput_w[c * 512 + k];
  q1s[c] = elu1(a0);
  __syncthreads();

  const float* lstmb = lstm + (size_t)b * SEQL * 512;
  int qlb = q_len[b];

  for (int t = 0; t < 4; t++) {
    // q_cmd[c], then u[c] = q_cmd[c]*cmd_w[c]
    float a1 = qT_b[t * 512 + c];
    const float* w = qT_w + ((size_t)t * 512 + c) * 512;
    for (int k = 0; k < 512; k++) a1 += q1s[k] * w[k];
    us[c] = a1 * cmd_w[c];
    __syncthreads();
    // raw_att partials: thread = s*16 + u
    {
      int s = c >> 4, u = c & 15;
      float p = 0.f;
      const float* lr = lstmb + s * 512;
      for (int r = u; r < 512; r += 16) p += us[r] * lr[r];
      red[c] = p;
    }
    __syncthreads();
    if (c < 32) {
      float raw = cmd_b[0];
      for (int u = 0; u < 16; u++) raw += red[c * 16 + u];
      raw = (c < qlb) ? raw : -1e30f;
      float mx = raw;
      for (int off = 16; off; off >>= 1) mx = fmaxf(mx, __shfl_xor(mx, off, 32));
      float e = expf(raw - mx);
      float sm = e;
      for (int off = 16; off; off >>= 1) sm += __shfl_xor(sm, off, 32);
      atts[c] = e / sm;
    }
    __syncthreads();
    float cd = 0.f;
    for (int s = 0; s < 32; s++) cd += atts[s] * lstmb[s * 512 + c];
    cmds[c] = cd;
    __syncthreads();
    float a2 = W_b[c];
    const float* w2 = W_w + (size_t)c * 1024 + 512;
    for (int k = 0; k < 512; k++) a2 += cmds[k] * w2[k];
    bias2[((size_t)(t * 64 + b) << 9) + c] = a2;
    __syncthreads();
  }
}

// ---------------------------------------------------------------------------
// 5-point stencil: y[b,n,:] = sum_{m in nbr(n)} x[b,m,:]   (bf16 in/out, f32 sum)
// n = i*32 + j; nbrs: self, n-32 (i>0), n+32 (i<31), n-1 (j>0), n+1 (j<31)
// ---------------------------------------------------------------------------
__global__ __launch_bounds__(256) void stencil_k(const unsigned short* __restrict__ x,
                                                 unsigned short* __restrict__ y) {
  int g = blockIdx.x * 256 + threadIdx.x;     // 4,194,304 granules of 8 bf16
  int v = g & 63;
  int n = (g >> 6) & 1023;
  int b = g >> 16;
  size_t base = ((((size_t)b << 10) + n) << 9) + v * 8;
  const unsigned short* p = x + base;
  float acc[8];
  short8 s = *(const short8*)p;
#pragma unroll
  for (int j = 0; j < 8; j++) acc[j] = bf2f((unsigned short)s[j]);
  int i = n >> 5, jj = n & 31;
  if (i > 0) {
    short8 t = *(const short8*)(p - 32 * 512);
#pragma unroll
    for (int j = 0; j < 8; j++) acc[j] += bf2f((unsigned short)t[j]);
  }
  if (i < 31) {
    short8 t = *(const short8*)(p + 32 * 512);
#pragma unroll
    for (int j = 0; j < 8; j++) acc[j] += bf2f((unsigned short)t[j]);
  }
  if (jj > 0) {
    short8 t = *(const short8*)(p - 512);
#pragma unroll
    for (int j = 0; j < 8; j++) acc[j] += bf2f((unsigned short)t[j]);
  }
  if (jj < 31) {
    short8 t = *(const short8*)(p + 512);
#pragma unroll
    for (int j = 0; j < 8; j++) acc[j] += bf2f((unsigned short)t[j]);
  }
  short8 o;
#pragma unroll
  for (int j = 0; j < 8; j++) o[j] = (short)f2bf(acc[j]);
  *(short8*)(y + base) = o;
}

// ---------------------------------------------------------------------------
// bf16 MFMA GEMM, C[M,512] = A[M,K] @ Bw[512,K]^T + bias, m97 structure:
// 128x128 tile, BK=32, 4 waves (2x2 of 64x64), 16x16x32 MFMA, global_load_lds.
// AF32: A is f32 (staged as f32 in LDS, converted at fragment read).
// MODE 0: +cbias[col],            no act, out bf16   (init GEMM)
// MODE 1: +deg(n)*bias2[b][col],  elu,    out bf16   (iters 0..2)
// MODE 2: +deg(n)*bias2[b][col],  no act, out f32    (iter 3 -> d_out)
// ---------------------------------------------------------------------------
template <int AF32, int MODE>
__global__ __launch_bounds__(256) void gemm_bt(
    const void* __restrict__ Ap, int lda,
    const unsigned short* __restrict__ Bw, int ldb, int K,
    const float* __restrict__ cbias, const float* __restrict__ bias2,
    void* __restrict__ Cp) {
  constexpr int ABYTES = AF32 ? 16384 : 8192;
  __shared__ __align__(128) char smem[ABYTES + 8192];
  char* As = smem;
  char* Bs = smem + ABYTES;

  const int tid = threadIdx.x;
  const int lane = tid & 63;
  const int wave = tid >> 6;
  const int wr = (wave >> 1) * 64;
  const int wc = (wave & 1) * 64;
  const int lr = lane & 15;
  const int lk = lane >> 4;

  // XCD-aware bijective swizzle (grid = 2048, divisible by 8); ntile inner so
  // the 4 n-tiles of one m-tile run adjacently on one XCD (A rows L2-hit).
  int bid = blockIdx.x;
  int cpx = gridDim.x >> 3;
  int wg = (bid & 7) * cpx + (bid >> 3);
  int mtile = wg >> 2;
  int ntile = wg & 3;
  const size_t rowBase = (size_t)mtile * 128;
  const int colBase = ntile * 128;

  floatx4 acc[4][4];
#pragma unroll
  for (int m = 0; m < 4; m++)
#pragma unroll
    for (int n = 0; n < 4; n++) acc[m][n] = {0.f, 0.f, 0.f, 0.f};

  for (int k0 = 0; k0 < K; k0 += 32) {
    __syncthreads();
    if constexpr (AF32) {
      const float* A = (const float*)Ap;
#pragma unroll
      for (int i = 0; i < 4; i++) {
        int g = tid + i * 256;  // 1024 granules: row=g>>3, seg=g&7
        gload16(A + (rowBase + (g >> 3)) * (size_t)lda + k0 + (g & 7) * 4, As + g * 16);
      }
    } else {
      const unsigned short* A = (const unsigned short*)Ap;
#pragma unroll
      for (int i = 0; i < 2; i++) {
        int g = tid + i * 256;  // 512 granules: row=g>>2, seg=g&3
        gload16(A + (rowBase + (g >> 2)) * (size_t)lda + k0 + (g & 3) * 8, As + g * 16);
      }
    }
#pragma unroll
    for (int i = 0; i < 2; i++) {
      int g = tid + i * 256;
      gload16(Bw + (size_t)(colBase + (g >> 2)) * ldb + k0 + (g & 3) * 8, Bs + g * 16);
    }
    __syncthreads();

    short8 a[4], b[4];
    if constexpr (AF32) {
#pragma unroll
      for (int m = 0; m < 4; m++) {
        const float* p = (const float*)As + (wr + m * 16 + lr) * 32 + lk * 8;
        short8 t;
#pragma unroll
        for (int j = 0; j < 8; j++) t[j] = (short)f2bf(p[j]);
        a[m] = t;
      }
    } else {
#pragma unroll
      for (int m = 0; m < 4; m++)
        a[m] = *(const short8*)((const unsigned short*)As + (wr + m * 16 + lr) * 32 + lk * 8);
    }
#pragma unroll
    for (int n = 0; n < 4; n++)
      b[n] = *(const short8*)((const unsigned short*)Bs + (wc + n * 16 + lr) * 32 + lk * 8);

#pragma unroll
    for (int m = 0; m < 4; m++)
#pragma unroll
      for (int n = 0; n < 4; n++)
        acc[m][n] = __builtin_amdgcn_mfma_f32_16x16x32_bf16(a[m], b[n], acc[m][n], 0, 0, 0);
  }

  // Epilogue: C/D layout col=lane&15, row=(lane>>4)*4+reg  [m89 verified]
#pragma unroll
  for (int m = 0; m < 4; m++) {
#pragma unroll
    for (int q = 0; q < 4; q++) {
      size_t grow = rowBase + wr + m * 16 + lk * 4 + q;
      float degf = 0.f;
      const float* b2 = nullptr;
      if constexpr (MODE != 0) {
        int nsp = (int)(grow & 1023);
        int ii = nsp >> 5, jj = nsp & 31;
        degf = (float)(1 + (ii > 0) + (ii < 31) + (jj > 0) + (jj < 31));
        b2 = bias2 + (grow >> 10) * CTXD;
      }
#pragma unroll
      for (int n = 0; n < 4; n++) {
        int gcol = colBase + wc + n * 16 + lr;
        float v = acc[m][n][q];
        if constexpr (MODE == 0) v += cbias[gcol];
        else v += degf * b2[gcol];
        if constexpr (MODE == 1) v = elu1(v);
        if constexpr (MODE == 2) ((float*)Cp)[grow * CTXD + gcol] = v;
        else ((unsigned short*)Cp)[grow * CTXD + gcol] = f2bf(v);
      }
    }
  }
}

// ---------------------------------------------------------------------------
extern "C" void kernel_launch(void* const* d_in, const int* in_sizes, int n_in,
                              void* d_out, int out_size, void* d_ws, size_t ws_size,
                              hipStream_t stream) {
  const float* images   = (const float*)d_in[0];
  const float* q_enc    = (const float*)d_in[1];
  const float* lstm     = (const float*)d_in[2];
  const int*   q_len    = (const int*)d_in[3];
  // d_in[4] = adj: implied by the 32x32 grid stencil, not read
  const float* initKB_w = (const float*)d_in[5];
  const float* initKB_b = (const float*)d_in[6];
  const float* W_w      = (const float*)d_in[7];
  const float* W_b      = (const float*)d_in[8];
  const float* qInput_w = (const float*)d_in[9];
  const float* qInput_b = (const float*)d_in[10];
  const float* qT_w     = (const float*)d_in[11];
  const float* qT_b     = (const float*)d_in[12];
  const float* cmd_w    = (const float*)d_in[13];
  const float* cmd_b    = (const float*)d_in[14];

  // ws layout (needs ~66 MB):
  //   y_bf16   : 64*1024*512*2 = 67108864
  //   kb_bf    : 512*1024*2    =  1048576
  //   w1_bf    : 512*512*2     =   524288
  //   bias2    : 4*64*512*4    =   524288
  char* ws = (char*)d_ws;
  unsigned short* y     = (unsigned short*)ws;
  unsigned short* kb_bf = (unsigned short*)(ws + 67108864);
  unsigned short* w1_bf = (unsigned short*)(ws + 68157440);
  float*          bias2 = (float*)(ws + 68681728);
  // x_loc (bf16, 64 MB) lives in d_out; final f32 GEMM overwrites d_out fully
  // and reads only y/bias2 — no overlap hazard.
  unsigned short* xloc  = (unsigned short*)d_out;

  pack_k<<<3072, 256, 0, stream>>>(initKB_w, W_w, kb_bf, w1_bf);
  cmd_pipeline<<<64, 512, 0, stream>>>(q_enc, lstm, q_len, qInput_w, qInput_b,
                                       qT_w, qT_b, cmd_w, cmd_b, W_w, W_b, bias2);

  // x_loc = images @ initKB_w^T + initKB_b   (no activation)
  gemm_bt<1, 0><<<2048, 256, 0, stream>>>(images, 1024, kb_bf, 1024, 1024,
                                          initKB_b, nullptr, xloc);

  for (int t = 0; t < 4; t++) {
    stencil_k<<<16384, 256, 0, stream>>>(xloc, y);
    if (t < 3)
      gemm_bt<0, 1><<<2048, 256, 0, stream>>>(y, 512, w1_bf, 512, 512,
                                              nullptr, bias2 + (size_t)t * 64 * 512, xloc);
    else
      gemm_bt<0, 2><<<2048, 256, 0, stream>>>(y, 512, w1_bf, 512, 512,
                                              nullptr, bias2 + (size_t)t * 64 * 512, d_out);
  }
}

// Round 2
// 625.683 us; speedup vs baseline: 1.3647x; 1.3647x over previous
//
#include <hip/hip_runtime.h>
#include <math.h>

// SpatialGNN: B=64, N=1024 (32x32 grid), D_FEAT=1024, CTX=512, S=32, T=4
#define NB 64
#define NNODES 1024
#define CTXD 512
#define SEQL 32

typedef __attribute__((ext_vector_type(8))) short short8;
typedef __attribute__((ext_vector_type(4))) float floatx4;

__device__ __forceinline__ float bf2f(unsigned short u) {
  union { unsigned int i; float f; } v; v.i = ((unsigned int)u) << 16; return v.f;
}
__device__ __forceinline__ unsigned short f2bf(float f) {
  union { float f; unsigned int i; } v; v.f = f;
  unsigned int r = v.i + 0x7fffu + ((v.i >> 16) & 1u);  // RNE
  return (unsigned short)(r >> 16);
}
__device__ __forceinline__ float elu1(float x) { return x > 0.f ? x : expm1f(x); }

__device__ __forceinline__ void gload16(const void* g, void* l) {
  __builtin_amdgcn_global_load_lds((const __attribute__((address_space(1))) void*)g,
                                   (__attribute__((address_space(3))) void*)l, 16, 0, 0);
}

// ---------------------------------------------------------------------------
// Pack: bf16 GEMM weights + f32 TRANSPOSED cmd-path weights (coalesced GEMV).
//   kb_bf [512c][1024k]  = initKB_w              (524288)
//   w1_bf [512c][512k]   = W_w[:, :512]          (262144)
//   qiT   [512k][512c]   = qInput_w^T            (262144)
//   qTT   [4][512k][512c]= qInputT_w^T per t     (1048576)
//   w2T   [512k][512c]   = W_w[:, 512:]^T        (262144)
// total 2359296 elems -> 9216 blocks x 256
// ---------------------------------------------------------------------------
__global__ __launch_bounds__(256) void pack_k(const float* __restrict__ kbw,
                                              const float* __restrict__ Ww,
                                              const float* __restrict__ qiw,
                                              const float* __restrict__ qtw,
                                              unsigned short* __restrict__ kb_bf,
                                              unsigned short* __restrict__ w1_bf,
                                              float* __restrict__ qiT,
                                              float* __restrict__ qTT,
                                              float* __restrict__ w2T) {
  int idx = blockIdx.x * 256 + threadIdx.x;
  if (idx < 524288) {
    kb_bf[idx] = f2bf(kbw[idx]);
  } else if (idx < 786432) {
    int o = idx - 524288;
    w1_bf[o] = f2bf(Ww[(o >> 9) * 1024 + (o & 511)]);
  } else if (idx < 1048576) {
    int o = idx - 786432;
    int k = o >> 9, c = o & 511;
    qiT[o] = qiw[c * 512 + k];
  } else if (idx < 2097152) {
    int o = idx - 1048576;
    int t = o >> 18, r = o & 262143;
    int k = r >> 9, c = r & 511;
    qTT[o] = qtw[((size_t)t * 512 + c) * 512 + k];
  } else {
    int o = idx - 2097152;
    int k = o >> 9, c = o & 511;
    w2T[o] = Ww[c * 1024 + 512 + k];
  }
}

// ---------------------------------------------------------------------------
// q1[b][c] = elu(q_enc[b] @ qInput_w^T + qInput_b)   — coalesced via qiT
// ---------------------------------------------------------------------------
__global__ __launch_bounds__(512) void q1_k(const float* __restrict__ q_enc,
                                            const float* __restrict__ qiT,
                                            const float* __restrict__ qInput_b,
                                            float* __restrict__ q1) {
  int b = blockIdx.x, c = threadIdx.x;
  __shared__ float qes[512];
  qes[c] = q_enc[b * 512 + c];
  __syncthreads();
  float a0 = qInput_b[c], a1 = 0.f, a2 = 0.f, a3 = 0.f;
#pragma unroll 4
  for (int k = 0; k < 512; k += 4) {
    a0 += qes[k] * qiT[k * 512 + c];
    a1 += qes[k + 1] * qiT[(k + 1) * 512 + c];
    a2 += qes[k + 2] * qiT[(k + 2) * 512 + c];
    a3 += qes[k + 3] * qiT[(k + 3) * 512 + c];
  }
  q1[b * 512 + c] = elu1(a0 + a1 + a2 + a3);
}

// ---------------------------------------------------------------------------
// Per (t,b): q_cmd -> raw_att -> softmax -> cmd -> bias2[t][b][:]
// All weight/lstm reads coalesced (c-parallel, k-serial).
// ---------------------------------------------------------------------------
__global__ __launch_bounds__(512) void cmdt_k(
    const float* __restrict__ q1, const float* __restrict__ lstm,
    const int* __restrict__ q_len,
    const float* __restrict__ qTT, const float* __restrict__ qT_b,
    const float* __restrict__ cmd_w, const float* __restrict__ cmd_b,
    const float* __restrict__ w2T, const float* __restrict__ W_b,
    float* __restrict__ bias2) {
  int b = blockIdx.x & 63;
  int t = blockIdx.x >> 6;
  int c = threadIdx.x;
  __shared__ float q1s[512];
  __shared__ float us[512];
  __shared__ float red[512];
  __shared__ float atts[32];
  __shared__ float cmds[512];

  q1s[c] = q1[b * 512 + c];
  __syncthreads();

  const float* wt = qTT + (size_t)t * 262144;
  float a0 = qT_b[t * 512 + c], a1 = 0.f, a2 = 0.f, a3 = 0.f;
#pragma unroll 4
  for (int k = 0; k < 512; k += 4) {
    a0 += q1s[k] * wt[k * 512 + c];
    a1 += q1s[k + 1] * wt[(k + 1) * 512 + c];
    a2 += q1s[k + 2] * wt[(k + 2) * 512 + c];
    a3 += q1s[k + 3] * wt[(k + 3) * 512 + c];
  }
  us[c] = (a0 + a1 + a2 + a3) * cmd_w[c];
  __syncthreads();

  const float* lstmb = lstm + (size_t)b * SEQL * 512;
  {
    int s = c >> 4, u = c & 15;
    float p = 0.f;
    const float* lr = lstmb + s * 512;
    for (int r = u; r < 512; r += 16) p += us[r] * lr[r];
    red[c] = p;
  }
  __syncthreads();
  if (c < 32) {
    float raw = cmd_b[0];
    for (int u = 0; u < 16; u++) raw += red[c * 16 + u];
    raw = (c < q_len[b]) ? raw : -1e30f;
    float mx = raw;
    for (int off = 16; off; off >>= 1) mx = fmaxf(mx, __shfl_xor(mx, off, 32));
    float e = expf(raw - mx);
    float sm = e;
    for (int off = 16; off; off >>= 1) sm += __shfl_xor(sm, off, 32);
    atts[c] = e / sm;
  }
  __syncthreads();
  float cd = 0.f;
#pragma unroll
  for (int s = 0; s < 32; s++) cd += atts[s] * lstmb[s * 512 + c];
  cmds[c] = cd;
  __syncthreads();

  float b0 = W_b[c], b1 = 0.f, b2 = 0.f, b3 = 0.f;
#pragma unroll 4
  for (int k = 0; k < 512; k += 4) {
    b0 += cmds[k] * w2T[k * 512 + c];
    b1 += cmds[k + 1] * w2T[(k + 1) * 512 + c];
    b2 += cmds[k + 2] * w2T[(k + 2) * 512 + c];
    b3 += cmds[k + 3] * w2T[(k + 3) * 512 + c];
  }
  bias2[((size_t)(t * 64 + b)) * 512 + c] = b0 + b1 + b2 + b3;
}

// ---------------------------------------------------------------------------
// 5-point stencil: y[b,n,:] = sum_{m in nbr(n)} x[b,m,:]   (bf16 in/out, f32 sum)
// ---------------------------------------------------------------------------
__global__ __launch_bounds__(256) void stencil_k(const unsigned short* __restrict__ x,
                                                 unsigned short* __restrict__ y) {
  int g = blockIdx.x * 256 + threadIdx.x;
  int v = g & 63;
  int n = (g >> 6) & 1023;
  int b = g >> 16;
  size_t base = ((((size_t)b << 10) + n) << 9) + v * 8;
  const unsigned short* p = x + base;
  float acc[8];
  short8 s = *(const short8*)p;
#pragma unroll
  for (int j = 0; j < 8; j++) acc[j] = bf2f((unsigned short)s[j]);
  int i = n >> 5, jj = n & 31;
  if (i > 0) {
    short8 t = *(const short8*)(p - 32 * 512);
#pragma unroll
    for (int j = 0; j < 8; j++) acc[j] += bf2f((unsigned short)t[j]);
  }
  if (i < 31) {
    short8 t = *(const short8*)(p + 32 * 512);
#pragma unroll
    for (int j = 0; j < 8; j++) acc[j] += bf2f((unsigned short)t[j]);
  }
  if (jj > 0) {
    short8 t = *(const short8*)(p - 512);
#pragma unroll
    for (int j = 0; j < 8; j++) acc[j] += bf2f((unsigned short)t[j]);
  }
  if (jj < 31) {
    short8 t = *(const short8*)(p + 512);
#pragma unroll
    for (int j = 0; j < 8; j++) acc[j] += bf2f((unsigned short)t[j]);
  }
  short8 o;
#pragma unroll
  for (int j = 0; j < 8; j++) o[j] = (short)f2bf(acc[j]);
  *(short8*)(y + base) = o;
}

// ---------------------------------------------------------------------------
// bf16 MFMA GEMM, C[M,512] = A[M,K] @ Bw[512,K]^T + bias, m97 structure.
// ---------------------------------------------------------------------------
template <int AF32, int MODE>
__global__ __launch_bounds__(256) void gemm_bt(
    const void* __restrict__ Ap, int lda,
    const unsigned short* __restrict__ Bw, int ldb, int K,
    const float* __restrict__ cbias, const float* __restrict__ bias2,
    void* __restrict__ Cp) {
  constexpr int ABYTES = AF32 ? 16384 : 8192;
  __shared__ __align__(128) char smem[ABYTES + 8192];
  char* As = smem;
  char* Bs = smem + ABYTES;

  const int tid = threadIdx.x;
  const int lane = tid & 63;
  const int wave = tid >> 6;
  const int wr = (wave >> 1) * 64;
  const int wc = (wave & 1) * 64;
  const int lr = lane & 15;
  const int lk = lane >> 4;

  int bid = blockIdx.x;
  int cpx = gridDim.x >> 3;
  int wg = (bid & 7) * cpx + (bid >> 3);
  int mtile = wg >> 2;
  int ntile = wg & 3;
  const size_t rowBase = (size_t)mtile * 128;
  const int colBase = ntile * 128;

  floatx4 acc[4][4];
#pragma unroll
  for (int m = 0; m < 4; m++)
#pragma unroll
    for (int n = 0; n < 4; n++) acc[m][n] = {0.f, 0.f, 0.f, 0.f};

  for (int k0 = 0; k0 < K; k0 += 32) {
    __syncthreads();
    if constexpr (AF32) {
      const float* A = (const float*)Ap;
#pragma unroll
      for (int i = 0; i < 4; i++) {
        int g = tid + i * 256;
        gload16(A + (rowBase + (g >> 3)) * (size_t)lda + k0 + (g & 7) * 4, As + g * 16);
      }
    } else {
      const unsigned short* A = (const unsigned short*)Ap;
#pragma unroll
      for (int i = 0; i < 2; i++) {
        int g = tid + i * 256;
        gload16(A + (rowBase + (g >> 2)) * (size_t)lda + k0 + (g & 3) * 8, As + g * 16);
      }
    }
#pragma unroll
    for (int i = 0; i < 2; i++) {
      int g = tid + i * 256;
      gload16(Bw + (size_t)(colBase + (g >> 2)) * ldb + k0 + (g & 3) * 8, Bs + g * 16);
    }
    __syncthreads();

    short8 a[4], b[4];
    if constexpr (AF32) {
#pragma unroll
      for (int m = 0; m < 4; m++) {
        const float* p = (const float*)As + (wr + m * 16 + lr) * 32 + lk * 8;
        short8 t;
#pragma unroll
        for (int j = 0; j < 8; j++) t[j] = (short)f2bf(p[j]);
        a[m] = t;
      }
    } else {
#pragma unroll
      for (int m = 0; m < 4; m++)
        a[m] = *(const short8*)((const unsigned short*)As + (wr + m * 16 + lr) * 32 + lk * 8);
    }
#pragma unroll
    for (int n = 0; n < 4; n++)
      b[n] = *(const short8*)((const unsigned short*)Bs + (wc + n * 16 + lr) * 32 + lk * 8);

#pragma unroll
    for (int m = 0; m < 4; m++)
#pragma unroll
      for (int n = 0; n < 4; n++)
        acc[m][n] = __builtin_amdgcn_mfma_f32_16x16x32_bf16(a[m], b[n], acc[m][n], 0, 0, 0);
  }

#pragma unroll
  for (int m = 0; m < 4; m++) {
#pragma unroll
    for (int q = 0; q < 4; q++) {
      size_t grow = rowBase + wr + m * 16 + lk * 4 + q;
      float degf = 0.f;
      const float* b2 = nullptr;
      if constexpr (MODE != 0) {
        int nsp = (int)(grow & 1023);
        int ii = nsp >> 5, jj = nsp & 31;
        degf = (float)(1 + (ii > 0) + (ii < 31) + (jj > 0) + (jj < 31));
        b2 = bias2 + (grow >> 10) * CTXD;
      }
#pragma unroll
      for (int n = 0; n < 4; n++) {
        int gcol = colBase + wc + n * 16 + lr;
        float v = acc[m][n][q];
        if constexpr (MODE == 0) v += cbias[gcol];
        else v += degf * b2[gcol];
        if constexpr (MODE == 1) v = elu1(v);
        if constexpr (MODE == 2) ((float*)Cp)[grow * CTXD + gcol] = v;
        else ((unsigned short*)Cp)[grow * CTXD + gcol] = f2bf(v);
      }
    }
  }
}

// ---------------------------------------------------------------------------
extern "C" void kernel_launch(void* const* d_in, const int* in_sizes, int n_in,
                              void* d_out, int out_size, void* d_ws, size_t ws_size,
                              hipStream_t stream) {
  const float* images   = (const float*)d_in[0];
  const float* q_enc    = (const float*)d_in[1];
  const float* lstm     = (const float*)d_in[2];
  const int*   q_len    = (const int*)d_in[3];
  // d_in[4] = adj: implied by the 32x32 grid stencil, not read
  const float* initKB_w = (const float*)d_in[5];
  const float* initKB_b = (const float*)d_in[6];
  const float* W_w      = (const float*)d_in[7];
  const float* W_b      = (const float*)d_in[8];
  const float* qInput_w = (const float*)d_in[9];
  const float* qInput_b = (const float*)d_in[10];
  const float* qT_w     = (const float*)d_in[11];
  const float* qT_b     = (const float*)d_in[12];
  const float* cmd_w    = (const float*)d_in[13];
  const float* cmd_b    = (const float*)d_in[14];

  // ws layout:
  //   y_bf16   : 64*1024*512*2 = 67108864   (transposed cmd weights aliased
  //              at the front of y — consumed by q1_k/cmdt_k BEFORE the first
  //              stencil_k writes y; stream-ordered, so no hazard)
  //   kb_bf    : 512*1024*2    =  1048576
  //   w1_bf    : 512*512*2     =   524288
  //   bias2    : 4*64*512*4    =   524288
  //   q1       : 64*512*4      =   131072
  char* ws = (char*)d_ws;
  unsigned short* y     = (unsigned short*)ws;
  float*          qiT   = (float*)ws;                    // 1 MB
  float*          qTT   = (float*)(ws + 1048576);        // 4 MB
  float*          w2T   = (float*)(ws + 5242880);        // 1 MB  (all < 6 MB, inside y)
  unsigned short* kb_bf = (unsigned short*)(ws + 67108864);
  unsigned short* w1_bf = (unsigned short*)(ws + 68157440);
  float*          bias2 = (float*)(ws + 68681728);
  float*          q1    = (float*)(ws + 69206016);
  unsigned short* xloc  = (unsigned short*)d_out;

  pack_k<<<9216, 256, 0, stream>>>(initKB_w, W_w, qInput_w, qT_w,
                                   kb_bf, w1_bf, qiT, qTT, w2T);
  q1_k<<<64, 512, 0, stream>>>(q_enc, qiT, qInput_b, q1);
  cmdt_k<<<256, 512, 0, stream>>>(q1, lstm, q_len, qTT, qT_b, cmd_w, cmd_b,
                                  w2T, W_b, bias2);

  // x_loc = images @ initKB_w^T + initKB_b   (no activation)
  gemm_bt<1, 0><<<2048, 256, 0, stream>>>(images, 1024, kb_bf, 1024, 1024,
                                          initKB_b, nullptr, xloc);

  for (int t = 0; t < 4; t++) {
    stencil_k<<<16384, 256, 0, stream>>>(xloc, y);
    if (t < 3)
      gemm_bt<0, 1><<<2048, 256, 0, stream>>>(y, 512, w1_bf, 512, 512,
                                              nullptr, bias2 + (size_t)t * 64 * 512, xloc);
    else
      gemm_bt<0, 2><<<2048, 256, 0, stream>>>(y, 512, w1_bf, 512, 512,
                                              nullptr, bias2 + (size_t)t * 64 * 512, d_out);
  }
}

// Round 3
// 544.300 us; speedup vs baseline: 1.5687x; 1.1495x over previous
//
#include <hip/hip_runtime.h>
#include <hip/hip_bf16.h>
#include <math.h>

// SpatialGNN: B=64, N=1024 (32x32 grid), D_FEAT=1024, CTX=512, S=32, T=4
#define NB 64
#define NNODES 1024
#define CTXD 512
#define SEQL 32

typedef __attribute__((ext_vector_type(8))) short short8;
typedef __attribute__((ext_vector_type(4))) float floatx4;

__device__ __forceinline__ float bf2f(unsigned short u) {
  union { unsigned int i; float f; } v; v.i = ((unsigned int)u) << 16; return v.f;
}
__device__ __forceinline__ unsigned short f2bf(float f) {
  union { float f; unsigned int i; } v; v.f = f;
  unsigned int r = v.i + 0x7fffu + ((v.i >> 16) & 1u);  // RNE
  return (unsigned short)(r >> 16);
}
__device__ __forceinline__ float elu1(float x) { return x > 0.f ? x : expm1f(x); }

__device__ __forceinline__ void gload16(const void* g, void* l) {
  __builtin_amdgcn_global_load_lds((const __attribute__((address_space(1))) void*)g,
                                   (__attribute__((address_space(3))) void*)l, 16, 0, 0);
}

// ---------------------------------------------------------------------------
// Pack: bf16 GEMM weights + f32 TRANSPOSED cmd-path weights (coalesced GEMV).
// ---------------------------------------------------------------------------
__global__ __launch_bounds__(256) void pack_k(const float* __restrict__ kbw,
                                              const float* __restrict__ Ww,
                                              const float* __restrict__ qiw,
                                              const float* __restrict__ qtw,
                                              unsigned short* __restrict__ kb_bf,
                                              unsigned short* __restrict__ w1_bf,
                                              float* __restrict__ qiT,
                                              float* __restrict__ qTT,
                                              float* __restrict__ w2T) {
  int idx = blockIdx.x * 256 + threadIdx.x;
  if (idx < 524288) {
    kb_bf[idx] = f2bf(kbw[idx]);
  } else if (idx < 786432) {
    int o = idx - 524288;
    w1_bf[o] = f2bf(Ww[(o >> 9) * 1024 + (o & 511)]);
  } else if (idx < 1048576) {
    int o = idx - 786432;
    int k = o >> 9, c = o & 511;
    qiT[o] = qiw[c * 512 + k];
  } else if (idx < 2097152) {
    int o = idx - 1048576;
    int t = o >> 18, r = o & 262143;
    int k = r >> 9, c = r & 511;
    qTT[o] = qtw[((size_t)t * 512 + c) * 512 + k];
  } else {
    int o = idx - 2097152;
    int k = o >> 9, c = o & 511;
    w2T[o] = Ww[c * 1024 + 512 + k];
  }
}

// ---------------------------------------------------------------------------
// q1[b][c] = elu(q_enc[b] @ qInput_w^T + qInput_b)
// ---------------------------------------------------------------------------
__global__ __launch_bounds__(512) void q1_k(const float* __restrict__ q_enc,
                                            const float* __restrict__ qiT,
                                            const float* __restrict__ qInput_b,
                                            float* __restrict__ q1) {
  int b = blockIdx.x, c = threadIdx.x;
  __shared__ float qes[512];
  qes[c] = q_enc[b * 512 + c];
  __syncthreads();
  float a0 = qInput_b[c], a1 = 0.f, a2 = 0.f, a3 = 0.f;
#pragma unroll 4
  for (int k = 0; k < 512; k += 4) {
    a0 += qes[k] * qiT[k * 512 + c];
    a1 += qes[k + 1] * qiT[(k + 1) * 512 + c];
    a2 += qes[k + 2] * qiT[(k + 2) * 512 + c];
    a3 += qes[k + 3] * qiT[(k + 3) * 512 + c];
  }
  q1[b * 512 + c] = elu1(a0 + a1 + a2 + a3);
}

// ---------------------------------------------------------------------------
// Per (t,b): q_cmd -> raw_att -> softmax -> cmd -> bias2[t][b][:]
// ---------------------------------------------------------------------------
__global__ __launch_bounds__(512) void cmdt_k(
    const float* __restrict__ q1, const float* __restrict__ lstm,
    const int* __restrict__ q_len,
    const float* __restrict__ qTT, const float* __restrict__ qT_b,
    const float* __restrict__ cmd_w, const float* __restrict__ cmd_b,
    const float* __restrict__ w2T, const float* __restrict__ W_b,
    float* __restrict__ bias2) {
  int b = blockIdx.x & 63;
  int t = blockIdx.x >> 6;
  int c = threadIdx.x;
  __shared__ float q1s[512];
  __shared__ float us[512];
  __shared__ float red[512];
  __shared__ float atts[32];
  __shared__ float cmds[512];

  q1s[c] = q1[b * 512 + c];
  __syncthreads();

  const float* wt = qTT + (size_t)t * 262144;
  float a0 = qT_b[t * 512 + c], a1 = 0.f, a2 = 0.f, a3 = 0.f;
#pragma unroll 4
  for (int k = 0; k < 512; k += 4) {
    a0 += q1s[k] * wt[k * 512 + c];
    a1 += q1s[k + 1] * wt[(k + 1) * 512 + c];
    a2 += q1s[k + 2] * wt[(k + 2) * 512 + c];
    a3 += q1s[k + 3] * wt[(k + 3) * 512 + c];
  }
  us[c] = (a0 + a1 + a2 + a3) * cmd_w[c];
  __syncthreads();

  const float* lstmb = lstm + (size_t)b * SEQL * 512;
  {
    int s = c >> 4, u = c & 15;
    float p = 0.f;
    const float* lr = lstmb + s * 512;
    for (int r = u; r < 512; r += 16) p += us[r] * lr[r];
    red[c] = p;
  }
  __syncthreads();
  if (c < 32) {
    float raw = cmd_b[0];
    for (int u = 0; u < 16; u++) raw += red[c * 16 + u];
    raw = (c < q_len[b]) ? raw : -1e30f;
    float mx = raw;
    for (int off = 16; off; off >>= 1) mx = fmaxf(mx, __shfl_xor(mx, off, 32));
    float e = expf(raw - mx);
    float sm = e;
    for (int off = 16; off; off >>= 1) sm += __shfl_xor(sm, off, 32);
    atts[c] = e / sm;
  }
  __syncthreads();
  float cd = 0.f;
#pragma unroll
  for (int s = 0; s < 32; s++) cd += atts[s] * lstmb[s * 512 + c];
  cmds[c] = cd;
  __syncthreads();

  float b0 = W_b[c], b1 = 0.f, b2 = 0.f, b3 = 0.f;
#pragma unroll 4
  for (int k = 0; k < 512; k += 4) {
    b0 += cmds[k] * w2T[k * 512 + c];
    b1 += cmds[k + 1] * w2T[(k + 1) * 512 + c];
    b2 += cmds[k + 2] * w2T[(k + 2) * 512 + c];
    b3 += cmds[k + 3] * w2T[(k + 3) * 512 + c];
  }
  bias2[((size_t)(t * 64 + b)) * 512 + c] = b0 + b1 + b2 + b3;
}

// ---------------------------------------------------------------------------
// 5-point stencil: y[b,n,:] = sum_{m in nbr(n)} x[b,m,:]   (bf16, f32 sum)
// ---------------------------------------------------------------------------
__global__ __launch_bounds__(256) void stencil_k(const unsigned short* __restrict__ x,
                                                 unsigned short* __restrict__ y) {
  int g = blockIdx.x * 256 + threadIdx.x;
  int v = g & 63;
  int n = (g >> 6) & 1023;
  int b = g >> 16;
  size_t base = ((((size_t)b << 10) + n) << 9) + v * 8;
  const unsigned short* p = x + base;
  float acc[8];
  short8 s = *(const short8*)p;
#pragma unroll
  for (int j = 0; j < 8; j++) acc[j] = bf2f((unsigned short)s[j]);
  int i = n >> 5, jj = n & 31;
  if (i > 0) {
    short8 t = *(const short8*)(p - 32 * 512);
#pragma unroll
    for (int j = 0; j < 8; j++) acc[j] += bf2f((unsigned short)t[j]);
  }
  if (i < 31) {
    short8 t = *(const short8*)(p + 32 * 512);
#pragma unroll
    for (int j = 0; j < 8; j++) acc[j] += bf2f((unsigned short)t[j]);
  }
  if (jj > 0) {
    short8 t = *(const short8*)(p - 512);
#pragma unroll
    for (int j = 0; j < 8; j++) acc[j] += bf2f((unsigned short)t[j]);
  }
  if (jj < 31) {
    short8 t = *(const short8*)(p + 512);
#pragma unroll
    for (int j = 0; j < 8; j++) acc[j] += bf2f((unsigned short)t[j]);
  }
  short8 o;
#pragma unroll
  for (int j = 0; j < 8; j++) o[j] = (short)f2bf(acc[j]);
  *(short8*)(y + base) = o;
}

// ---------------------------------------------------------------------------
// bf16 MFMA GEMM, C[M,512] = A[M,K] @ Bw[512,K]^T + bias.
// 128x128 tile, BK=64, XOR-swizzled LDS (slot = s ^ (row&7), 16B granules):
//  - bf16 A / B staged via global_load_lds with PRE-SWIZZLED global source
//    (linear LDS dest, rule #21 / m173 pattern)
//  - AF32 A reg-staged: coalesced f32 loads -> bf16 cvt -> swizzled ds_write
//  - fragment ds_read_b128 at same XOR -> 2-way banks (free)
// MODE 0: +cbias[col],           no act, out bf16   (init GEMM)
// MODE 1: +deg(n)*bias2[b][col], elu,    out bf16   (iters 0..2)
// MODE 2: +deg(n)*bias2[b][col], no act, out f32    (iter 3 -> d_out)
// ---------------------------------------------------------------------------
template <int AF32, int MODE>
__global__ __launch_bounds__(256) void gemm_bt(
    const void* __restrict__ Ap, int lda,
    const unsigned short* __restrict__ Bw, int ldb, int K,
    const float* __restrict__ cbias, const float* __restrict__ bias2,
    void* __restrict__ Cp) {
  __shared__ __align__(128) unsigned short As[128 * 64];  // 16 KB, swizzled
  __shared__ __align__(128) unsigned short Bs[128 * 64];  // 16 KB, swizzled

  const int tid = threadIdx.x;
  const int lane = tid & 63;
  const int wave = tid >> 6;
  const int wr = (wave >> 1) * 64;
  const int wc = (wave & 1) * 64;
  const int lr = lane & 15;
  const int lk = lane >> 4;
  const int lr7 = lr & 7;

  // XCD-aware bijective swizzle (grid = 2048, divisible by 8)
  int bid = blockIdx.x;
  int cpx = gridDim.x >> 3;
  int wg = (bid & 7) * cpx + (bid >> 3);
  int mtile = wg >> 2;
  int ntile = wg & 3;
  const size_t rowBase = (size_t)mtile * 128;
  const int colBase = ntile * 128;

  floatx4 acc[4][4];
#pragma unroll
  for (int m = 0; m < 4; m++)
#pragma unroll
    for (int n = 0; n < 4; n++) acc[m][n] = {0.f, 0.f, 0.f, 0.f};

  for (int k0 = 0; k0 < K; k0 += 64) {
    __syncthreads();
    if constexpr (AF32) {
      // reg-stage: logical granule (r,s) -> swizzled LDS slot (r, s^(r&7))
      const float* A = (const float*)Ap;
#pragma unroll
      for (int j = 0; j < 4; j++) {
        int g = j * 256 + tid;
        int r = g >> 3, s = g & 7;
        const float* src = A + (rowBase + r) * (size_t)lda + k0 + s * 8;
        floatx4 v0 = *(const floatx4*)src;
        floatx4 v1 = *(const floatx4*)(src + 4);
        short8 t;
#pragma unroll
        for (int e = 0; e < 4; e++) {
          __hip_bfloat16 h0 = __float2bfloat16(v0[e]);
          __hip_bfloat16 h1 = __float2bfloat16(v1[e]);
          t[e] = (short)*reinterpret_cast<unsigned short*>(&h0);
          t[e + 4] = (short)*reinterpret_cast<unsigned short*>(&h1);
        }
        *(short8*)((char*)As + r * 128 + ((s ^ (r & 7)) << 4)) = t;
      }
    } else {
      // global_load_lds: linear LDS dest, swizzled global source column
      const unsigned short* A = (const unsigned short*)Ap;
#pragma unroll
      for (int j = 0; j < 4; j++) {
        int g = j * 256 + tid;
        int r = g >> 3, u = g & 7;
        gload16(A + (rowBase + r) * (size_t)lda + k0 + ((u ^ (r & 7)) << 3),
                (char*)As + g * 16);
      }
    }
#pragma unroll
    for (int j = 0; j < 4; j++) {
      int g = j * 256 + tid;
      int r = g >> 3, u = g & 7;
      gload16(Bw + (size_t)(colBase + r) * ldb + k0 + ((u ^ (r & 7)) << 3),
              (char*)Bs + g * 16);
    }
    __syncthreads();

#pragma unroll
    for (int kk = 0; kk < 2; kk++) {
      const int ub = ((kk << 2) + lk) ^ lr7;
      short8 a[4], b[4];
#pragma unroll
      for (int m = 0; m < 4; m++)
        a[m] = *(const short8*)((const char*)As + (wr + m * 16 + lr) * 128 + (ub << 4));
#pragma unroll
      for (int n = 0; n < 4; n++)
        b[n] = *(const short8*)((const char*)Bs + (wc + n * 16 + lr) * 128 + (ub << 4));
#pragma unroll
      for (int m = 0; m < 4; m++)
#pragma unroll
        for (int n = 0; n < 4; n++)
          acc[m][n] = __builtin_amdgcn_mfma_f32_16x16x32_bf16(a[m], b[n], acc[m][n], 0, 0, 0);
    }
  }

  // Epilogue: C/D layout col=lane&15, row=(lane>>4)*4+reg  [m89 verified]
#pragma unroll
  for (int m = 0; m < 4; m++) {
#pragma unroll
    for (int q = 0; q < 4; q++) {
      size_t grow = rowBase + wr + m * 16 + lk * 4 + q;
      float degf = 0.f;
      const float* b2 = nullptr;
      if constexpr (MODE != 0) {
        int nsp = (int)(grow & 1023);
        int ii = nsp >> 5, jj = nsp & 31;
        degf = (float)(1 + (ii > 0) + (ii < 31) + (jj > 0) + (jj < 31));
        b2 = bias2 + (grow >> 10) * CTXD;
      }
#pragma unroll
      for (int n = 0; n < 4; n++) {
        int gcol = colBase + wc + n * 16 + lr;
        float v = acc[m][n][q];
        if constexpr (MODE == 0) v += cbias[gcol];
        else v += degf * b2[gcol];
        if constexpr (MODE == 1) v = elu1(v);
        if constexpr (MODE == 2) ((float*)Cp)[grow * CTXD + gcol] = v;
        else ((unsigned short*)Cp)[grow * CTXD + gcol] = f2bf(v);
      }
    }
  }
}

// ---------------------------------------------------------------------------
extern "C" void kernel_launch(void* const* d_in, const int* in_sizes, int n_in,
                              void* d_out, int out_size, void* d_ws, size_t ws_size,
                              hipStream_t stream) {
  const float* images   = (const float*)d_in[0];
  const float* q_enc    = (const float*)d_in[1];
  const float* lstm     = (const float*)d_in[2];
  const int*   q_len    = (const int*)d_in[3];
  // d_in[4] = adj: implied by the 32x32 grid stencil, not read
  const float* initKB_w = (const float*)d_in[5];
  const float* initKB_b = (const float*)d_in[6];
  const float* W_w      = (const float*)d_in[7];
  const float* W_b      = (const float*)d_in[8];
  const float* qInput_w = (const float*)d_in[9];
  const float* qInput_b = (const float*)d_in[10];
  const float* qT_w     = (const float*)d_in[11];
  const float* qT_b     = (const float*)d_in[12];
  const float* cmd_w    = (const float*)d_in[13];
  const float* cmd_b    = (const float*)d_in[14];

  // ws layout:
  //   y_bf16   : 64*1024*512*2 = 67108864   (transposed cmd weights aliased at
  //              the front — consumed by q1_k/cmdt_k before first stencil_k)
  //   kb_bf / w1_bf / bias2 / q1 after
  char* ws = (char*)d_ws;
  unsigned short* y     = (unsigned short*)ws;
  float*          qiT   = (float*)ws;                    // 1 MB
  float*          qTT   = (float*)(ws + 1048576);        // 4 MB
  float*          w2T   = (float*)(ws + 5242880);        // 1 MB
  unsigned short* kb_bf = (unsigned short*)(ws + 67108864);
  unsigned short* w1_bf = (unsigned short*)(ws + 68157440);
  float*          bias2 = (float*)(ws + 68681728);
  float*          q1    = (float*)(ws + 69206016);
  unsigned short* xloc  = (unsigned short*)d_out;

  pack_k<<<9216, 256, 0, stream>>>(initKB_w, W_w, qInput_w, qT_w,
                                   kb_bf, w1_bf, qiT, qTT, w2T);
  q1_k<<<64, 512, 0, stream>>>(q_enc, qiT, qInput_b, q1);
  cmdt_k<<<256, 512, 0, stream>>>(q1, lstm, q_len, qTT, qT_b, cmd_w, cmd_b,
                                  w2T, W_b, bias2);

  // x_loc = images @ initKB_w^T + initKB_b
  gemm_bt<1, 0><<<2048, 256, 0, stream>>>(images, 1024, kb_bf, 1024, 1024,
                                          initKB_b, nullptr, xloc);

  for (int t = 0; t < 4; t++) {
    stencil_k<<<16384, 256, 0, stream>>>(xloc, y);
    if (t < 3)
      gemm_bt<0, 1><<<2048, 256, 0, stream>>>(y, 512, w1_bf, 512, 512,
                                              nullptr, bias2 + (size_t)t * 64 * 512, xloc);
    else
      gemm_bt<0, 2><<<2048, 256, 0, stream>>>(y, 512, w1_bf, 512, 512,
                                              nullptr, bias2 + (size_t)t * 64 * 512, d_out);
  }
}